// Round 1
// baseline (414.130 us; speedup 1.0000x reference)
//
#include <hip/hip_runtime.h>
#include <stdint.h>

typedef unsigned short u16;
typedef __bf16 bf16x8 __attribute__((ext_vector_type(8)));
typedef float f32x4 __attribute__((ext_vector_type(4)));

#define K_DIM 4096
#define N_OUT 4096
#define M_ROWS 8192

// ---------- helpers ----------

__device__ __forceinline__ u16 f2bf(float f) {
    // round-to-nearest-even f32 -> bf16 (inputs are finite)
    uint32_t u = __builtin_bit_cast(uint32_t, f);
    u += 0x7fffu + ((u >> 16) & 1u);
    return (u16)(u >> 16);
}

__device__ __forceinline__ void gload_lds16(const void* g, void* l) {
    __builtin_amdgcn_global_load_lds(
        (const __attribute__((address_space(1))) void*)g,
        (__attribute__((address_space(3))) void*)l,
        16, 0, 0);
}

// Distinguish mask pushed as int32 (values 0/1, bytes 1..3 of each word zero)
// from mask pushed as 1-byte bools (random 0/1 bytes -> some word > 1).
__device__ __forceinline__ int mask_is_int32(const void* maskp) {
    const uint32_t* u = (const uint32_t*)maskp;
    int ok = 1;
#pragma unroll
    for (int g = 0; g < 16; ++g) ok &= (u[g] <= 1u);
    return ok;
}

// ---------- prep kernels ----------

__global__ __launch_bounds__(256) void cvt_x_kernel(const float* __restrict__ x,
                                                    u16* __restrict__ xb) {
    size_t t = (size_t)blockIdx.x * 256 + threadIdx.x;  // 4194304 threads, 8 elems each
    const float4* p = (const float4*)x + t * 2;
    float4 a = p[0], b = p[1];
    union { u16 u[8]; uint4 v; } o;
    o.u[0] = f2bf(a.x); o.u[1] = f2bf(a.y); o.u[2] = f2bf(a.z); o.u[3] = f2bf(a.w);
    o.u[4] = f2bf(b.x); o.u[5] = f2bf(b.y); o.u[6] = f2bf(b.z); o.u[7] = f2bf(b.w);
    ((uint4*)xb)[t] = o.v;
}

__global__ __launch_bounds__(256) void build_w_kernel(const int* __restrict__ wq,
                                                      const float* __restrict__ qscale,
                                                      const float* __restrict__ qzero,
                                                      const float* __restrict__ theta,
                                                      const void* __restrict__ maskp,
                                                      u16* __restrict__ wb) {
    const int mi32 = mask_is_int32(maskp);
    size_t t = (size_t)blockIdx.x * 256 + threadIdx.x;  // 2097152 threads, 8 elems each
    size_t base = t * 8;
    int o = (int)(base >> 12);  // / 4096
    float s = qscale[o], z = qzero[o];

    int4 q0 = ((const int4*)wq)[t * 2];
    int4 q1 = ((const int4*)wq)[t * 2 + 1];
    float4 th0 = ((const float4*)theta)[t * 2];
    float4 th1 = ((const float4*)theta)[t * 2 + 1];

    int mv[8];
    if (mi32) {
        int4 m0 = ((const int4*)maskp)[t * 2];
        int4 m1 = ((const int4*)maskp)[t * 2 + 1];
        mv[0] = m0.x; mv[1] = m0.y; mv[2] = m0.z; mv[3] = m0.w;
        mv[4] = m1.x; mv[5] = m1.y; mv[6] = m1.z; mv[7] = m1.w;
    } else {
        uint2 mm = ((const uint2*)maskp)[t];
#pragma unroll
        for (int j = 0; j < 4; ++j) mv[j] = (mm.x >> (8 * j)) & 0xff;
#pragma unroll
        for (int j = 0; j < 4; ++j) mv[4 + j] = (mm.y >> (8 * j)) & 0xff;
    }

    float w[8];
    w[0] = mv[0] ? ((float)q0.x - z) * s : th0.x;
    w[1] = mv[1] ? ((float)q0.y - z) * s : th0.y;
    w[2] = mv[2] ? ((float)q0.z - z) * s : th0.z;
    w[3] = mv[3] ? ((float)q0.w - z) * s : th0.w;
    w[4] = mv[4] ? ((float)q1.x - z) * s : th1.x;
    w[5] = mv[5] ? ((float)q1.y - z) * s : th1.y;
    w[6] = mv[6] ? ((float)q1.z - z) * s : th1.z;
    w[7] = mv[7] ? ((float)q1.w - z) * s : th1.w;

    union { u16 u[8]; uint4 v; } ob;
#pragma unroll
    for (int j = 0; j < 8; ++j) ob.u[j] = f2bf(w[j]);
    ((uint4*)wb)[t] = ob.v;
}

// ---------- main GEMM (m97 structure: 128x128 tile, BK=32, 4 waves) ----------

__global__ __launch_bounds__(256) void gemm_kernel(const u16* __restrict__ xb,
                                                   const u16* __restrict__ wb,
                                                   const float* __restrict__ bias,
                                                   float* __restrict__ out) {
    __shared__ u16 As[128 * 32];  // [row][k]  8 KB
    __shared__ u16 Bs[128 * 32];  // [col][k]  8 KB

    const int tid = threadIdx.x;
    const int wave = tid >> 6, lane = tid & 63;
    const int n0 = blockIdx.x * 128;
    const int m0 = blockIdx.y * 128;
    const int wr = (wave >> 1) * 64;   // wave row offset in tile
    const int wc = (wave & 1) * 64;    // wave col offset in tile
    const int lr = lane & 15;
    const int lk = (lane >> 4) * 8;

    f32x4 acc[4][4];
    const f32x4 zero = {0.f, 0.f, 0.f, 0.f};
#pragma unroll
    for (int m = 0; m < 4; ++m)
#pragma unroll
        for (int n = 0; n < 4; ++n) acc[m][n] = zero;

    // staging: 8 chunks of 1024B per tile; wave handles chunks {2w, 2w+1}
    const int c0 = wave * 2;
    const int srow = c0 * 16 + (lane >> 2);
    const int skc = (lane & 3) * 8;
    const u16* gA0 = xb + (size_t)(m0 + srow) * K_DIM + skc;
    const u16* gA1 = gA0 + (size_t)16 * K_DIM;
    const u16* gB0 = wb + (size_t)(n0 + srow) * K_DIM + skc;
    const u16* gB1 = gB0 + (size_t)16 * K_DIM;
    u16* lA0 = &As[c0 * 512];
    u16* lA1 = &As[(c0 + 1) * 512];
    u16* lB0 = &Bs[c0 * 512];
    u16* lB1 = &Bs[(c0 + 1) * 512];

    int aoff[4], boff[4];
#pragma unroll
    for (int m = 0; m < 4; ++m) aoff[m] = (wr + m * 16 + lr) * 32 + lk;
#pragma unroll
    for (int n = 0; n < 4; ++n) boff[n] = (wc + n * 16 + lr) * 32 + lk;

    for (int k0 = 0; k0 < K_DIM; k0 += 32) {
        gload_lds16(gA0 + k0, lA0);
        gload_lds16(gA1 + k0, lA1);
        gload_lds16(gB0 + k0, lB0);
        gload_lds16(gB1 + k0, lB1);
        __syncthreads();

        bf16x8 af[4], bfr[4];
#pragma unroll
        for (int m = 0; m < 4; ++m) af[m] = *(const bf16x8*)&As[aoff[m]];
#pragma unroll
        for (int n = 0; n < 4; ++n) bfr[n] = *(const bf16x8*)&Bs[boff[n]];
#pragma unroll
        for (int m = 0; m < 4; ++m)
#pragma unroll
            for (int n = 0; n < 4; ++n)
                acc[m][n] = __builtin_amdgcn_mfma_f32_16x16x32_bf16(af[m], bfr[n], acc[m][n], 0, 0, 0);
        __syncthreads();
    }

    // epilogue: C/D layout col = lane&15, row = (lane>>4)*4 + reg
    const int rbase = m0 + wr + (lane >> 4) * 4;
    const int cbase = n0 + wc + lr;
#pragma unroll
    for (int n = 0; n < 4; ++n) {
        const int col = cbase + n * 16;
        const float bv = bias[col];
#pragma unroll
        for (int m = 0; m < 4; ++m) {
            f32x4 v = acc[m][n];
            const int r0 = rbase + m * 16;
#pragma unroll
            for (int r = 0; r < 4; ++r)
                out[(size_t)(r0 + r) * N_OUT + col] = v[r] + bv;
        }
    }
}

// ---------- correct-but-slow fallback (only if ws too small) ----------

__global__ __launch_bounds__(256) void fallback_kernel(const float* __restrict__ x,
                                                       const int* __restrict__ wq,
                                                       const float* __restrict__ qscale,
                                                       const float* __restrict__ qzero,
                                                       const float* __restrict__ theta,
                                                       const void* __restrict__ maskp,
                                                       const float* __restrict__ bias,
                                                       float* __restrict__ out) {
    __shared__ float xs[64][17];
    __shared__ float wsh[64][17];
    const int mi32 = mask_is_int32(maskp);
    const int n0 = blockIdx.x * 64, m0 = blockIdx.y * 64;
    const int t = threadIdx.x;
    const int tr = t >> 4, tc = t & 15;
    float acc[4][4] = {};

    for (int k0 = 0; k0 < K_DIM; k0 += 16) {
#pragma unroll
        for (int j = 0; j < 4; ++j) {
            int e = t * 4 + j;
            int r = e >> 4, c = e & 15;
            xs[r][c] = x[(size_t)(m0 + r) * K_DIM + k0 + c];
            int o = n0 + r;
            size_t idx = (size_t)o * K_DIM + k0 + c;
            float dq = ((float)wq[idx] - qzero[o]) * qscale[o];
            int mv = mi32 ? ((const int*)maskp)[idx] : ((const unsigned char*)maskp)[idx];
            wsh[r][c] = mv ? dq : theta[idx];
        }
        __syncthreads();
#pragma unroll
        for (int kk = 0; kk < 16; ++kk) {
            float a4[4], b4[4];
#pragma unroll
            for (int i = 0; i < 4; ++i) a4[i] = xs[tr * 4 + i][kk];
#pragma unroll
            for (int i = 0; i < 4; ++i) b4[i] = wsh[tc * 4 + i][kk];
#pragma unroll
            for (int i = 0; i < 4; ++i)
#pragma unroll
                for (int j = 0; j < 4; ++j) acc[i][j] += a4[i] * b4[j];
        }
        __syncthreads();
    }
#pragma unroll
    for (int i = 0; i < 4; ++i)
#pragma unroll
        for (int j = 0; j < 4; ++j)
            out[(size_t)(m0 + tr * 4 + i) * N_OUT + n0 + tc * 4 + j] =
                acc[i][j] + bias[n0 + tc * 4 + j];
}

// ---------- launch ----------

extern "C" void kernel_launch(void* const* d_in, const int* in_sizes, int n_in,
                              void* d_out, int out_size, void* d_ws, size_t ws_size,
                              hipStream_t stream) {
    const float* x      = (const float*)d_in[0];
    const int*   wq     = (const int*)d_in[1];
    const float* qscale = (const float*)d_in[2];
    const float* qzero  = (const float*)d_in[3];
    const float* theta  = (const float*)d_in[4];
    const void*  mask   = d_in[5];
    const float* bias   = (const float*)d_in[6];
    float* out = (float*)d_out;

    const size_t xb_bytes = (size_t)M_ROWS * K_DIM * 2;   // 67108864
    const size_t wb_bytes = (size_t)N_OUT * K_DIM * 2;    // 33554432

    if (ws_size >= xb_bytes + wb_bytes) {
        u16* xb = (u16*)d_ws;
        u16* wb = (u16*)((char*)d_ws + xb_bytes);
        cvt_x_kernel<<<16384, 256, 0, stream>>>(x, xb);
        build_w_kernel<<<8192, 256, 0, stream>>>(wq, qscale, qzero, theta, mask, wb);
        dim3 grid(N_OUT / 128, M_ROWS / 128);
        gemm_kernel<<<grid, 256, 0, stream>>>(xb, wb, bias, out);
    } else {
        dim3 grid(N_OUT / 64, M_ROWS / 64);
        fallback_kernel<<<grid, 256, 0, stream>>>(x, wq, qscale, qzero, theta, mask, bias, out);
    }
}

// Round 2
// 340.516 us; speedup vs baseline: 1.2162x; 1.2162x over previous
//
#include <hip/hip_runtime.h>
#include <stdint.h>

typedef unsigned short u16;
typedef __bf16 bf16x8 __attribute__((ext_vector_type(8)));
typedef float f32x4 __attribute__((ext_vector_type(4)));

#define K_DIM 4096
#define N_OUT 4096
#define M_ROWS 8192

// ---------- helpers ----------

__device__ __forceinline__ u16 f2bf(float f) {
    uint32_t u = __builtin_bit_cast(uint32_t, f);
    u += 0x7fffu + ((u >> 16) & 1u);
    return (u16)(u >> 16);
}

__device__ __forceinline__ void gload_lds16(const void* g, void* l) {
    __builtin_amdgcn_global_load_lds(
        (const __attribute__((address_space(1))) void*)g,
        (__attribute__((address_space(3))) void*)l,
        16, 0, 0);
}

__device__ __forceinline__ int mask_is_int32(const void* maskp) {
    const uint32_t* u = (const uint32_t*)maskp;
    int ok = 1;
#pragma unroll
    for (int g = 0; g < 16; ++g) ok &= (u[g] <= 1u);
    return ok;
}

// ---------- prep kernels (unchanged, ~54us combined, near BW floor) ----------

__global__ __launch_bounds__(256) void cvt_x_kernel(const float* __restrict__ x,
                                                    u16* __restrict__ xb) {
    size_t t = (size_t)blockIdx.x * 256 + threadIdx.x;
    const float4* p = (const float4*)x + t * 2;
    float4 a = p[0], b = p[1];
    union { u16 u[8]; uint4 v; } o;
    o.u[0] = f2bf(a.x); o.u[1] = f2bf(a.y); o.u[2] = f2bf(a.z); o.u[3] = f2bf(a.w);
    o.u[4] = f2bf(b.x); o.u[5] = f2bf(b.y); o.u[6] = f2bf(b.z); o.u[7] = f2bf(b.w);
    ((uint4*)xb)[t] = o.v;
}

__global__ __launch_bounds__(256) void build_w_kernel(const int* __restrict__ wq,
                                                      const float* __restrict__ qscale,
                                                      const float* __restrict__ qzero,
                                                      const float* __restrict__ theta,
                                                      const void* __restrict__ maskp,
                                                      u16* __restrict__ wb) {
    const int mi32 = mask_is_int32(maskp);
    size_t t = (size_t)blockIdx.x * 256 + threadIdx.x;
    size_t base = t * 8;
    int o = (int)(base >> 12);
    float s = qscale[o], z = qzero[o];

    int4 q0 = ((const int4*)wq)[t * 2];
    int4 q1 = ((const int4*)wq)[t * 2 + 1];
    float4 th0 = ((const float4*)theta)[t * 2];
    float4 th1 = ((const float4*)theta)[t * 2 + 1];

    int mv[8];
    if (mi32) {
        int4 m0 = ((const int4*)maskp)[t * 2];
        int4 m1 = ((const int4*)maskp)[t * 2 + 1];
        mv[0] = m0.x; mv[1] = m0.y; mv[2] = m0.z; mv[3] = m0.w;
        mv[4] = m1.x; mv[5] = m1.y; mv[6] = m1.z; mv[7] = m1.w;
    } else {
        uint2 mm = ((const uint2*)maskp)[t];
#pragma unroll
        for (int j = 0; j < 4; ++j) mv[j] = (mm.x >> (8 * j)) & 0xff;
#pragma unroll
        for (int j = 0; j < 4; ++j) mv[4 + j] = (mm.y >> (8 * j)) & 0xff;
    }

    float w[8];
    w[0] = mv[0] ? ((float)q0.x - z) * s : th0.x;
    w[1] = mv[1] ? ((float)q0.y - z) * s : th0.y;
    w[2] = mv[2] ? ((float)q0.z - z) * s : th0.z;
    w[3] = mv[3] ? ((float)q0.w - z) * s : th0.w;
    w[4] = mv[4] ? ((float)q1.x - z) * s : th1.x;
    w[5] = mv[5] ? ((float)q1.y - z) * s : th1.y;
    w[6] = mv[6] ? ((float)q1.z - z) * s : th1.z;
    w[7] = mv[7] ? ((float)q1.w - z) * s : th1.w;

    union { u16 u[8]; uint4 v; } ob;
#pragma unroll
    for (int j = 0; j < 8; ++j) ob.u[j] = f2bf(w[j]);
    ((uint4*)wb)[t] = ob.v;
}

// ---------- 256x256 8-phase GEMM (T2+T3+T4+T5 per the 8-phase template) ----------
//
// LDS: A = [2 dbuf][2 khalf][256 rows][32 cols] bf16 (4 planes x 16KiB), B same.
// Swizzle: within each 64B row (4 x 16B slots), phys_slot = log_slot ^ (row&3).
//   Write side: gload_lds writes linearly; per-lane GLOBAL source is pre-swizzled
//   (lane l sources k-chunk (l&3)^((l>>2)&3)), so LDS(row,s) holds chunk s^(row&3).
//   Read side: ds_read addr uses slot (l>>4)^(l&3). Both-sides involution (rule #21).
// Phase staging schedule (iter j computes tiles 2j [buf0], 2j+1 [buf1]):
//   P1:A[b1]k1<-2j+1  P2:B[b1]k1<-2j+1  P3:A[b0]k0<-2j+2  P4:B[b0]k0<-2j+2 vmcnt(4)
//   P5:A[b0]k1<-2j+2  P6:B[b0]k1<-2j+2  P7:A[b1]k0<-2j+3  P8:B[b1]k0<-2j+3 vmcnt(4)
// Every plane: staged >=1 barrier after its last read; drained by a vmcnt(4)
// before its first read (verified plane-by-plane).

__global__ __launch_bounds__(512, 2) void gemm8_kernel(const u16* __restrict__ xb,
                                                       const u16* __restrict__ wb,
                                                       const float* __restrict__ bias,
                                                       float* __restrict__ out) {
    __shared__ u16 lds[65536];  // 128 KiB: A planes [0,32768), B planes [32768,65536)

    const int tid = threadIdx.x;
    const int lane = tid & 63, wave = tid >> 6;
    const int wm = wave >> 2, wn = wave & 3;
    const int m0 = blockIdx.y * 256, n0 = blockIdx.x * 256;

    // fragment-read addressing (u16 units)
    const int a_r = wm * 128 + (lane & 15);
    const int b_r = wn * 64 + (lane & 15);
    const int rslot = ((lane >> 4) ^ (lane & 3)) * 8;

    // stage addressing: wave w instr i covers chunk c=w*2+i = rows [c*16,+16) of a plane
    const int ch0 = wave * 2, ch1 = ch0 + 1;
    const int sRow = lane >> 2;
    const int sK = (((lane & 3) ^ ((lane >> 2) & 3)) * 8);
    const u16* gA0 = xb + (size_t)(m0 + ch0 * 16 + sRow) * K_DIM + sK;
    const u16* gA1 = xb + (size_t)(m0 + ch1 * 16 + sRow) * K_DIM + sK;
    const u16* gB0 = wb + (size_t)(n0 + ch0 * 16 + sRow) * K_DIM + sK;
    const u16* gB1 = wb + (size_t)(n0 + ch1 * 16 + sRow) * K_DIM + sK;

    f32x4 acc[8][4];
    const f32x4 zero = {0.f, 0.f, 0.f, 0.f};
#pragma unroll
    for (int m = 0; m < 8; ++m)
#pragma unroll
        for (int n = 0; n < 4; ++n) acc[m][n] = zero;

#define SA(BUF, KH, KT) { \
    const size_t kofs = (size_t)((KT) * 64 + (KH) * 32); \
    const int pl = ((BUF) * 2 + (KH)) * 8192; \
    gload_lds16(gA0 + kofs, &lds[pl + ch0 * 512]); \
    gload_lds16(gA1 + kofs, &lds[pl + ch1 * 512]); }
#define SB(BUF, KH, KT) { \
    const size_t kofs = (size_t)((KT) * 64 + (KH) * 32); \
    const int pl = 32768 + ((BUF) * 2 + (KH)) * 8192; \
    gload_lds16(gB0 + kofs, &lds[pl + ch0 * 512]); \
    gload_lds16(gB1 + kofs, &lds[pl + ch1 * 512]); }
#define DA(BUF, KS, MH) { \
    const int pa = ((BUF) * 2 + (KS)) * 8192 + (a_r + (MH) * 64) * 32 + rslot; \
    af[0] = *(const bf16x8*)&lds[pa]; \
    af[1] = *(const bf16x8*)&lds[pa + 512]; \
    af[2] = *(const bf16x8*)&lds[pa + 1024]; \
    af[3] = *(const bf16x8*)&lds[pa + 1536]; }
#define DB(BUF, KS) { \
    const int pb = 32768 + ((BUF) * 2 + (KS)) * 8192 + b_r * 32 + rslot; \
    bfr[0] = *(const bf16x8*)&lds[pb]; \
    bfr[1] = *(const bf16x8*)&lds[pb + 512]; \
    bfr[2] = *(const bf16x8*)&lds[pb + 1024]; \
    bfr[3] = *(const bf16x8*)&lds[pb + 1536]; }
#define MM(MH, M2) \
    acc[(MH)*4+(M2)][0] = __builtin_amdgcn_mfma_f32_16x16x32_bf16(af[M2], bfr[0], acc[(MH)*4+(M2)][0], 0, 0, 0); \
    acc[(MH)*4+(M2)][1] = __builtin_amdgcn_mfma_f32_16x16x32_bf16(af[M2], bfr[1], acc[(MH)*4+(M2)][1], 0, 0, 0); \
    acc[(MH)*4+(M2)][2] = __builtin_amdgcn_mfma_f32_16x16x32_bf16(af[M2], bfr[2], acc[(MH)*4+(M2)][2], 0, 0, 0); \
    acc[(MH)*4+(M2)][3] = __builtin_amdgcn_mfma_f32_16x16x32_bf16(af[M2], bfr[3], acc[(MH)*4+(M2)][3], 0, 0, 0);
#define MFMA16(MH) { \
    __builtin_amdgcn_s_setprio(1); \
    MM(MH, 0) MM(MH, 1) MM(MH, 2) MM(MH, 3) \
    __builtin_amdgcn_s_setprio(0); }
#define BAR() __builtin_amdgcn_s_barrier()
#define SCHED0() __builtin_amdgcn_sched_barrier(0)
#define VMW4() asm volatile("s_waitcnt vmcnt(4)" ::: "memory")

    // prologue: tile0 full + tile1 khalf0
    SA(0, 0, 0); SB(0, 0, 0);
    SA(0, 1, 0); SB(0, 1, 0);
    SA(1, 0, 1); SB(1, 0, 1);
    asm volatile("s_waitcnt vmcnt(0)" ::: "memory");
    BAR();

#pragma unroll 1
    for (int j = 0; j < K_DIM / 128; ++j) {
        const int t1 = 2 * j + 1;
        const int t2 = (2 * j + 2) & 63;
        const int t3 = (2 * j + 3) & 63;
        bf16x8 af[4], bfr[4];
        // P1
        DB(0, 0); DA(0, 0, 0); SA(1, 1, t1);
        BAR(); MFMA16(0); SCHED0(); BAR();
        // P2
        DA(0, 0, 1); SB(1, 1, t1);
        BAR(); MFMA16(1); SCHED0(); BAR();
        // P3
        DB(0, 1); DA(0, 1, 0); SA(0, 0, t2);
        BAR(); MFMA16(0); SCHED0(); BAR();
        // P4
        DA(0, 1, 1); SB(0, 0, t2);
        BAR(); MFMA16(1); VMW4(); SCHED0(); BAR();
        // P5
        DB(1, 0); DA(1, 0, 0); SA(0, 1, t2);
        BAR(); MFMA16(0); SCHED0(); BAR();
        // P6
        DA(1, 0, 1); SB(0, 1, t2);
        BAR(); MFMA16(1); SCHED0(); BAR();
        // P7
        DB(1, 1); DA(1, 1, 0); SA(1, 0, t3);
        BAR(); MFMA16(0); SCHED0(); BAR();
        // P8
        DA(1, 1, 1); SB(1, 0, t3);
        BAR(); MFMA16(1); VMW4(); SCHED0(); BAR();
    }

    // drain trailing prefetches so no gload lands in deallocated LDS
    asm volatile("s_waitcnt vmcnt(0)" ::: "memory");

    // epilogue: C/D layout col=lane&15, row=(lane>>4)*4+reg
    const int rowBase = m0 + wm * 128 + ((lane >> 4) << 2);
    const int colBase = n0 + wn * 64 + (lane & 15);
#pragma unroll
    for (int n = 0; n < 4; ++n) {
        const int col = colBase + n * 16;
        const float bv = bias[col];
#pragma unroll
        for (int m = 0; m < 8; ++m) {
            const f32x4 v = acc[m][n];
            float* o = out + (size_t)(rowBase + m * 16) * N_OUT + col;
            o[0] = v[0] + bv;
            o[N_OUT] = v[1] + bv;
            o[2 * N_OUT] = v[2] + bv;
            o[3 * N_OUT] = v[3] + bv;
        }
    }
#undef SA
#undef SB
#undef DA
#undef DB
#undef MM
#undef MFMA16
#undef BAR
#undef SCHED0
#undef VMW4
}

// ---------- correct-but-slow fallback (only if ws too small) ----------

__global__ __launch_bounds__(256) void fallback_kernel(const float* __restrict__ x,
                                                       const int* __restrict__ wq,
                                                       const float* __restrict__ qscale,
                                                       const float* __restrict__ qzero,
                                                       const float* __restrict__ theta,
                                                       const void* __restrict__ maskp,
                                                       const float* __restrict__ bias,
                                                       float* __restrict__ out) {
    __shared__ float xs[64][17];
    __shared__ float wsh[64][17];
    const int mi32 = mask_is_int32(maskp);
    const int n0 = blockIdx.x * 64, m0 = blockIdx.y * 64;
    const int t = threadIdx.x;
    const int tr = t >> 4, tc = t & 15;
    float acc[4][4] = {};

    for (int k0 = 0; k0 < K_DIM; k0 += 16) {
#pragma unroll
        for (int j = 0; j < 4; ++j) {
            int e = t * 4 + j;
            int r = e >> 4, c = e & 15;
            xs[r][c] = x[(size_t)(m0 + r) * K_DIM + k0 + c];
            int o = n0 + r;
            size_t idx = (size_t)o * K_DIM + k0 + c;
            float dq = ((float)wq[idx] - qzero[o]) * qscale[o];
            int mv = mi32 ? ((const int*)maskp)[idx] : ((const unsigned char*)maskp)[idx];
            wsh[r][c] = mv ? dq : theta[idx];
        }
        __syncthreads();
#pragma unroll
        for (int kk = 0; kk < 16; ++kk) {
            float a4[4], b4[4];
#pragma unroll
            for (int i = 0; i < 4; ++i) a4[i] = xs[tr * 4 + i][kk];
#pragma unroll
            for (int i = 0; i < 4; ++i) b4[i] = wsh[tc * 4 + i][kk];
#pragma unroll
            for (int i = 0; i < 4; ++i)
#pragma unroll
                for (int j = 0; j < 4; ++j) acc[i][j] += a4[i] * b4[j];
        }
        __syncthreads();
    }
#pragma unroll
    for (int i = 0; i < 4; ++i)
#pragma unroll
        for (int j = 0; j < 4; ++j)
            out[(size_t)(m0 + tr * 4 + i) * N_OUT + n0 + tc * 4 + j] =
                acc[i][j] + bias[n0 + tc * 4 + j];
}

// ---------- launch ----------

extern "C" void kernel_launch(void* const* d_in, const int* in_sizes, int n_in,
                              void* d_out, int out_size, void* d_ws, size_t ws_size,
                              hipStream_t stream) {
    const float* x      = (const float*)d_in[0];
    const int*   wq     = (const int*)d_in[1];
    const float* qscale = (const float*)d_in[2];
    const float* qzero  = (const float*)d_in[3];
    const float* theta  = (const float*)d_in[4];
    const void*  mask   = d_in[5];
    const float* bias   = (const float*)d_in[6];
    float* out = (float*)d_out;

    const size_t xb_bytes = (size_t)M_ROWS * K_DIM * 2;
    const size_t wb_bytes = (size_t)N_OUT * K_DIM * 2;

    if (ws_size >= xb_bytes + wb_bytes) {
        u16* xb = (u16*)d_ws;
        u16* wb = (u16*)((char*)d_ws + xb_bytes);
        cvt_x_kernel<<<16384, 256, 0, stream>>>(x, xb);
        build_w_kernel<<<8192, 256, 0, stream>>>(wq, qscale, qzero, theta, mask, wb);
        dim3 grid(N_OUT / 256, M_ROWS / 256);
        gemm8_kernel<<<grid, 512, 0, stream>>>(xb, wb, bias, out);
    } else {
        dim3 grid(N_OUT / 64, M_ROWS / 64);
        fallback_kernel<<<grid, 256, 0, stream>>>(x, wq, qscale, qzero, theta, mask, bias, out);
    }
}

// Round 3
// 326.993 us; speedup vs baseline: 1.2665x; 1.0414x over previous
//
#include <hip/hip_runtime.h>
#include <stdint.h>

typedef unsigned short u16;
typedef __bf16 bf16x8 __attribute__((ext_vector_type(8)));
typedef float f32x4 __attribute__((ext_vector_type(4)));

#define K_DIM 4096
#define N_OUT 4096
#define M_ROWS 8192

// ---------- helpers ----------

__device__ __forceinline__ u16 f2bf(float f) {
    uint32_t u = __builtin_bit_cast(uint32_t, f);
    u += 0x7fffu + ((u >> 16) & 1u);
    return (u16)(u >> 16);
}

__device__ __forceinline__ void gload_lds16(const void* g, void* l) {
    __builtin_amdgcn_global_load_lds(
        (const __attribute__((address_space(1))) void*)g,
        (__attribute__((address_space(3))) void*)l,
        16, 0, 0);
}

__device__ __forceinline__ int mask_is_int32(const void* maskp) {
    const uint32_t* u = (const uint32_t*)maskp;
    int ok = 1;
#pragma unroll
    for (int g = 0; g < 16; ++g) ok &= (u[g] <= 1u);
    return ok;
}

// ---------- prep kernels (~54us combined, near BW floor) ----------

__global__ __launch_bounds__(256) void cvt_x_kernel(const float* __restrict__ x,
                                                    u16* __restrict__ xb) {
    size_t t = (size_t)blockIdx.x * 256 + threadIdx.x;
    const float4* p = (const float4*)x + t * 2;
    float4 a = p[0], b = p[1];
    union { u16 u[8]; uint4 v; } o;
    o.u[0] = f2bf(a.x); o.u[1] = f2bf(a.y); o.u[2] = f2bf(a.z); o.u[3] = f2bf(a.w);
    o.u[4] = f2bf(b.x); o.u[5] = f2bf(b.y); o.u[6] = f2bf(b.z); o.u[7] = f2bf(b.w);
    ((uint4*)xb)[t] = o.v;
}

__global__ __launch_bounds__(256) void build_w_kernel(const int* __restrict__ wq,
                                                      const float* __restrict__ qscale,
                                                      const float* __restrict__ qzero,
                                                      const float* __restrict__ theta,
                                                      const void* __restrict__ maskp,
                                                      u16* __restrict__ wb) {
    const int mi32 = mask_is_int32(maskp);
    size_t t = (size_t)blockIdx.x * 256 + threadIdx.x;
    size_t base = t * 8;
    int o = (int)(base >> 12);
    float s = qscale[o], z = qzero[o];

    int4 q0 = ((const int4*)wq)[t * 2];
    int4 q1 = ((const int4*)wq)[t * 2 + 1];
    float4 th0 = ((const float4*)theta)[t * 2];
    float4 th1 = ((const float4*)theta)[t * 2 + 1];

    int mv[8];
    if (mi32) {
        int4 m0 = ((const int4*)maskp)[t * 2];
        int4 m1 = ((const int4*)maskp)[t * 2 + 1];
        mv[0] = m0.x; mv[1] = m0.y; mv[2] = m0.z; mv[3] = m0.w;
        mv[4] = m1.x; mv[5] = m1.y; mv[6] = m1.z; mv[7] = m1.w;
    } else {
        uint2 mm = ((const uint2*)maskp)[t];
#pragma unroll
        for (int j = 0; j < 4; ++j) mv[j] = (mm.x >> (8 * j)) & 0xff;
#pragma unroll
        for (int j = 0; j < 4; ++j) mv[4 + j] = (mm.y >> (8 * j)) & 0xff;
    }

    float w[8];
    w[0] = mv[0] ? ((float)q0.x - z) * s : th0.x;
    w[1] = mv[1] ? ((float)q0.y - z) * s : th0.y;
    w[2] = mv[2] ? ((float)q0.z - z) * s : th0.z;
    w[3] = mv[3] ? ((float)q0.w - z) * s : th0.w;
    w[4] = mv[4] ? ((float)q1.x - z) * s : th1.x;
    w[5] = mv[5] ? ((float)q1.y - z) * s : th1.y;
    w[6] = mv[6] ? ((float)q1.z - z) * s : th1.z;
    w[7] = mv[7] ? ((float)q1.w - z) * s : th1.w;

    union { u16 u[8]; uint4 v; } ob;
#pragma unroll
    for (int j = 0; j < 8; ++j) ob.u[j] = f2bf(w[j]);
    ((uint4*)wb)[t] = ob.v;
}

// ---------- 256x256 8-phase GEMM (T2+T3+T4+T5) ----------
//
// LDS: A = [2 dbuf][2 khalf][256 rows][32 cols] bf16 (4 planes x 16KiB), B same.
// Swizzle (v2): within each 64B row (4 x 16B slots), phys_slot = log_slot ^ h(row&15)
// with h(r) = (r>>1)&3 (row bits 1-2, decoupled from bank-parity bit row&1).
// Read: lane l -> row r = l&15, log_slot q = l>>4; phys_slot = q ^ ((l>>1)&3).
//   Bank_start = (r&1)*16 + phys_slot*4: every consecutive 8-lane group covers all
//   8 bank-quads = all 32 banks (was 4 quads 2x with h(r)=r&3 -> 2.5e7 conflicts).
// Write: gload_lds writes linearly; staged row&15 = lane>>2, so per-lane GLOBAL
//   source chunk = (l&3) ^ ((l>>3)&3). Both sides use the same involution (rule #21).
// Phase staging schedule (iter j computes tiles 2j [buf0], 2j+1 [buf1]):
//   P1:A[b1]k1<-2j+1  P2:B[b1]k1<-2j+1  P3:A[b0]k0<-2j+2  P4:B[b0]k0<-2j+2 vmcnt(4)
//   P5:A[b0]k1<-2j+2  P6:B[b0]k1<-2j+2  P7:A[b1]k0<-2j+3  P8:B[b1]k0<-2j+3 vmcnt(4)

__global__ __launch_bounds__(512, 2) void gemm8_kernel(const u16* __restrict__ xb,
                                                       const u16* __restrict__ wb,
                                                       const float* __restrict__ bias,
                                                       float* __restrict__ out) {
    __shared__ u16 lds[65536];  // 128 KiB: A planes [0,32768), B planes [32768,65536)

    const int tid = threadIdx.x;
    const int lane = tid & 63, wave = tid >> 6;
    const int wm = wave >> 2, wn = wave & 3;
    const int m0 = blockIdx.y * 256, n0 = blockIdx.x * 256;

    // fragment-read addressing (u16 units)
    const int a_r = wm * 128 + (lane & 15);
    const int b_r = wn * 64 + (lane & 15);
    const int rslot = ((lane >> 4) ^ ((lane >> 1) & 3)) * 8;

    // stage addressing: wave w instr i covers chunk c=w*2+i = rows [c*16,+16) of a plane
    const int ch0 = wave * 2, ch1 = ch0 + 1;
    const int sRow = lane >> 2;
    const int sK = (((lane & 3) ^ ((lane >> 3) & 3)) * 8);
    const u16* gA0 = xb + (size_t)(m0 + ch0 * 16 + sRow) * K_DIM + sK;
    const u16* gA1 = xb + (size_t)(m0 + ch1 * 16 + sRow) * K_DIM + sK;
    const u16* gB0 = wb + (size_t)(n0 + ch0 * 16 + sRow) * K_DIM + sK;
    const u16* gB1 = wb + (size_t)(n0 + ch1 * 16 + sRow) * K_DIM + sK;

    f32x4 acc[8][4];
    const f32x4 zero = {0.f, 0.f, 0.f, 0.f};
#pragma unroll
    for (int m = 0; m < 8; ++m)
#pragma unroll
        for (int n = 0; n < 4; ++n) acc[m][n] = zero;

#define SA(BUF, KH, KT) { \
    const size_t kofs = (size_t)((KT) * 64 + (KH) * 32); \
    const int pl = ((BUF) * 2 + (KH)) * 8192; \
    gload_lds16(gA0 + kofs, &lds[pl + ch0 * 512]); \
    gload_lds16(gA1 + kofs, &lds[pl + ch1 * 512]); }
#define SB(BUF, KH, KT) { \
    const size_t kofs = (size_t)((KT) * 64 + (KH) * 32); \
    const int pl = 32768 + ((BUF) * 2 + (KH)) * 8192; \
    gload_lds16(gB0 + kofs, &lds[pl + ch0 * 512]); \
    gload_lds16(gB1 + kofs, &lds[pl + ch1 * 512]); }
#define DA(BUF, KS, MH) { \
    const int pa = ((BUF) * 2 + (KS)) * 8192 + (a_r + (MH) * 64) * 32 + rslot; \
    af[0] = *(const bf16x8*)&lds[pa]; \
    af[1] = *(const bf16x8*)&lds[pa + 512]; \
    af[2] = *(const bf16x8*)&lds[pa + 1024]; \
    af[3] = *(const bf16x8*)&lds[pa + 1536]; }
#define DB(BUF, KS) { \
    const int pb = 32768 + ((BUF) * 2 + (KS)) * 8192 + b_r * 32 + rslot; \
    bfr[0] = *(const bf16x8*)&lds[pb]; \
    bfr[1] = *(const bf16x8*)&lds[pb + 512]; \
    bfr[2] = *(const bf16x8*)&lds[pb + 1024]; \
    bfr[3] = *(const bf16x8*)&lds[pb + 1536]; }
#define MM(MH, M2) \
    acc[(MH)*4+(M2)][0] = __builtin_amdgcn_mfma_f32_16x16x32_bf16(af[M2], bfr[0], acc[(MH)*4+(M2)][0], 0, 0, 0); \
    acc[(MH)*4+(M2)][1] = __builtin_amdgcn_mfma_f32_16x16x32_bf16(af[M2], bfr[1], acc[(MH)*4+(M2)][1], 0, 0, 0); \
    acc[(MH)*4+(M2)][2] = __builtin_amdgcn_mfma_f32_16x16x32_bf16(af[M2], bfr[2], acc[(MH)*4+(M2)][2], 0, 0, 0); \
    acc[(MH)*4+(M2)][3] = __builtin_amdgcn_mfma_f32_16x16x32_bf16(af[M2], bfr[3], acc[(MH)*4+(M2)][3], 0, 0, 0);
#define MFMA16(MH) { \
    __builtin_amdgcn_s_setprio(1); \
    MM(MH, 0) MM(MH, 1) MM(MH, 2) MM(MH, 3) \
    __builtin_amdgcn_s_setprio(0); }
#define BAR() __builtin_amdgcn_s_barrier()
#define SCHED0() __builtin_amdgcn_sched_barrier(0)
#define VMW4() asm volatile("s_waitcnt vmcnt(4)" ::: "memory")

    // prologue: tile0 full + tile1 khalf0
    SA(0, 0, 0); SB(0, 0, 0);
    SA(0, 1, 0); SB(0, 1, 0);
    SA(1, 0, 1); SB(1, 0, 1);
    asm volatile("s_waitcnt vmcnt(0)" ::: "memory");
    BAR();

#pragma unroll 1
    for (int j = 0; j < K_DIM / 128; ++j) {
        const int t1 = 2 * j + 1;
        const int t2 = (2 * j + 2) & 63;
        const int t3 = (2 * j + 3) & 63;
        bf16x8 af[4], bfr[4];
        // P1
        DB(0, 0); DA(0, 0, 0); SA(1, 1, t1);
        BAR(); MFMA16(0); SCHED0(); BAR();
        // P2
        DA(0, 0, 1); SB(1, 1, t1);
        BAR(); MFMA16(1); SCHED0(); BAR();
        // P3
        DB(0, 1); DA(0, 1, 0); SA(0, 0, t2);
        BAR(); MFMA16(0); SCHED0(); BAR();
        // P4
        DA(0, 1, 1); SB(0, 0, t2);
        BAR(); MFMA16(1); VMW4(); SCHED0(); BAR();
        // P5
        DB(1, 0); DA(1, 0, 0); SA(0, 1, t2);
        BAR(); MFMA16(0); SCHED0(); BAR();
        // P6
        DA(1, 0, 1); SB(0, 1, t2);
        BAR(); MFMA16(1); SCHED0(); BAR();
        // P7
        DB(1, 1); DA(1, 1, 0); SA(1, 0, t3);
        BAR(); MFMA16(0); SCHED0(); BAR();
        // P8
        DA(1, 1, 1); SB(1, 0, t3);
        BAR(); MFMA16(1); VMW4(); SCHED0(); BAR();
    }

    // drain trailing prefetches so no gload lands in deallocated LDS
    asm volatile("s_waitcnt vmcnt(0)" ::: "memory");

    // epilogue: C/D layout col=lane&15, row=(lane>>4)*4+reg
    const int rowBase = m0 + wm * 128 + ((lane >> 4) << 2);
    const int colBase = n0 + wn * 64 + (lane & 15);
#pragma unroll
    for (int n = 0; n < 4; ++n) {
        const int col = colBase + n * 16;
        const float bv = bias[col];
#pragma unroll
        for (int m = 0; m < 8; ++m) {
            const f32x4 v = acc[m][n];
            float* o = out + (size_t)(rowBase + m * 16) * N_OUT + col;
            o[0] = v[0] + bv;
            o[N_OUT] = v[1] + bv;
            o[2 * N_OUT] = v[2] + bv;
            o[3 * N_OUT] = v[3] + bv;
        }
    }
#undef SA
#undef SB
#undef DA
#undef DB
#undef MM
#undef MFMA16
#undef BAR
#undef SCHED0
#undef VMW4
}

// ---------- correct-but-slow fallback (only if ws too small) ----------

__global__ __launch_bounds__(256) void fallback_kernel(const float* __restrict__ x,
                                                       const int* __restrict__ wq,
                                                       const float* __restrict__ qscale,
                                                       const float* __restrict__ qzero,
                                                       const float* __restrict__ theta,
                                                       const void* __restrict__ maskp,
                                                       const float* __restrict__ bias,
                                                       float* __restrict__ out) {
    __shared__ float xs[64][17];
    __shared__ float wsh[64][17];
    const int mi32 = mask_is_int32(maskp);
    const int n0 = blockIdx.x * 64, m0 = blockIdx.y * 64;
    const int t = threadIdx.x;
    const int tr = t >> 4, tc = t & 15;
    float acc[4][4] = {};

    for (int k0 = 0; k0 < K_DIM; k0 += 16) {
#pragma unroll
        for (int j = 0; j < 4; ++j) {
            int e = t * 4 + j;
            int r = e >> 4, c = e & 15;
            xs[r][c] = x[(size_t)(m0 + r) * K_DIM + k0 + c];
            int o = n0 + r;
            size_t idx = (size_t)o * K_DIM + k0 + c;
            float dq = ((float)wq[idx] - qzero[o]) * qscale[o];
            int mv = mi32 ? ((const int*)maskp)[idx] : ((const unsigned char*)maskp)[idx];
            wsh[r][c] = mv ? dq : theta[idx];
        }
        __syncthreads();
#pragma unroll
        for (int kk = 0; kk < 16; ++kk) {
            float a4[4], b4[4];
#pragma unroll
            for (int i = 0; i < 4; ++i) a4[i] = xs[tr * 4 + i][kk];
#pragma unroll
            for (int i = 0; i < 4; ++i) b4[i] = wsh[tc * 4 + i][kk];
#pragma unroll
            for (int i = 0; i < 4; ++i)
#pragma unroll
                for (int j = 0; j < 4; ++j) acc[i][j] += a4[i] * b4[j];
        }
        __syncthreads();
    }
#pragma unroll
    for (int i = 0; i < 4; ++i)
#pragma unroll
        for (int j = 0; j < 4; ++j)
            out[(size_t)(m0 + tr * 4 + i) * N_OUT + n0 + tc * 4 + j] =
                acc[i][j] + bias[n0 + tc * 4 + j];
}

// ---------- launch ----------

extern "C" void kernel_launch(void* const* d_in, const int* in_sizes, int n_in,
                              void* d_out, int out_size, void* d_ws, size_t ws_size,
                              hipStream_t stream) {
    const float* x      = (const float*)d_in[0];
    const int*   wq     = (const int*)d_in[1];
    const float* qscale = (const float*)d_in[2];
    const float* qzero  = (const float*)d_in[3];
    const float* theta  = (const float*)d_in[4];
    const void*  mask   = d_in[5];
    const float* bias   = (const float*)d_in[6];
    float* out = (float*)d_out;

    const size_t xb_bytes = (size_t)M_ROWS * K_DIM * 2;
    const size_t wb_bytes = (size_t)N_OUT * K_DIM * 2;

    if (ws_size >= xb_bytes + wb_bytes) {
        u16* xb = (u16*)d_ws;
        u16* wb = (u16*)((char*)d_ws + xb_bytes);
        cvt_x_kernel<<<16384, 256, 0, stream>>>(x, xb);
        build_w_kernel<<<8192, 256, 0, stream>>>(wq, qscale, qzero, theta, mask, wb);
        dim3 grid(N_OUT / 256, M_ROWS / 256);
        gemm8_kernel<<<grid, 512, 0, stream>>>(xb, wb, bias, out);
    } else {
        dim3 grid(N_OUT / 64, M_ROWS / 64);
        fallback_kernel<<<grid, 256, 0, stream>>>(x, wq, qscale, qzero, theta, mask, bias, out);
    }
}